// Round 10
// baseline (1572.074 us; speedup 1.0000x reference)
//
#include <hip/hip_runtime.h>
#include <math.h>

#define N_NODES 100000
#define N_EDGES 3200000
#define HDIM 128

// ---- bucket sort CSR build ----
#define NB 196        // buckets of 512 consecutive dst nodes (100000/512 -> 196)
#define BSH 9         // 512 nodes per bucket
#define BSLOT 18432   // tmp slots per bucket (avg fill 16327, +16 sigma headroom)

typedef __attribute__((ext_vector_type(8))) short bf16x8;
typedef __attribute__((ext_vector_type(4))) float f32x4;

__device__ __forceinline__ unsigned short f2bf(float f) {
  union { float f; unsigned u; } v; v.f = f;
  unsigned r = v.u + 0x7fffu + ((v.u >> 16) & 1u);
  return (unsigned short)(r >> 16);
}
__device__ __forceinline__ float bflo(unsigned p) {
  union { unsigned u; float f; } v; v.u = p << 16; return v.f;
}
__device__ __forceinline__ float bfhi(unsigned p) {
  union { unsigned u; float f; } v; v.u = p & 0xffff0000u; return v.f;
}
// fast sigmoid/tanh: v_exp + v_rcp (approx err ~1e-6 << bf16 quantum 4e-3
// already present in the data path).
__device__ __forceinline__ float fsigmoid(float v) {
  return __builtin_amdgcn_rcpf(1.f + __expf(-v));
}
__device__ __forceinline__ float ftanh(float v) {
  return 1.f - 2.f * __builtin_amdgcn_rcpf(1.f + __expf(2.f * v));
}

// ---------------------------------------------------------------------------
__global__ __launch_bounds__(256) void zero_i32(int* __restrict__ p, int n) {
  int i = blockIdx.x * 256 + threadIdx.x;
  if (i < n) p[i] = 0;
}
__global__ __launch_bounds__(256) void zero_f32(float* __restrict__ p, int n) {
  int i = blockIdx.x * 256 + threadIdx.x;
  if (i < n) p[i] = 0.f;
}

// ---------------------------------------------------------------------------
// Repack a [384][128] fp32 weight matrix (row-major [col][k]) into
// MFMA-B-fragment-ordered bf16 (lane*16B contiguous per fragment).
// ---------------------------------------------------------------------------
__global__ __launch_bounds__(256) void repack_frag_b(
    const float* __restrict__ src, short* __restrict__ dst)
{
  int o = blockIdx.x * 256 + threadIdx.x;      // 0 .. 384*128-1
  if (o >= 384 * 128) return;
  int j    = o & 7;
  int lane = (o >> 3) & 63;
  int ks   = (o >> 9) & 3;
  int t    = o >> 11;
  int m  = lane & 15;
  int g4 = lane >> 4;
  dst[o] = (short)f2bf(src[(t * 16 + m) * 128 + ks * 32 + g4 * 8 + j]);
}

// ---------------------------------------------------------------------------
// Tiled fp32 GEMM, K fixed at 128 (emb, weight folds). Optional bf16-pack
// epilogue mirror (xpack != nullptr -> also emit packed bf16 rows).
// ---------------------------------------------------------------------------
template<bool BT>
__global__ __launch_bounds__(256) void gemm_k128(
    const float* __restrict__ A, const float* __restrict__ W,
    const float* __restrict__ bias, float* __restrict__ Y,
    unsigned* __restrict__ xpack, int M, int OUT)
{
  __shared__ alignas(16) float lds_a[32 * 68];
  __shared__ alignas(16) float lds_b[32 * 132];
  const int tid = threadIdx.x;
  const int tx = tid & 15;
  const int ty = tid >> 4;
  const int rowBase = blockIdx.x * 64;
  const int colBase = blockIdx.y * 128;

  float acc[4][8];
#pragma unroll
  for (int r = 0; r < 4; r++)
#pragma unroll
    for (int c = 0; c < 8; c++) acc[r][c] = 0.f;

  for (int k0 = 0; k0 < 128; k0 += 32) {
#pragma unroll
    for (int i = 0; i < 2; i++) {
      int idx = tid + i * 256;
      int r   = idx >> 3;
      int kk  = (idx & 7) << 2;
      int gr  = rowBase + r;
      float4 v = make_float4(0.f, 0.f, 0.f, 0.f);
      if (gr < M) v = *(const float4*)(A + (size_t)gr * HDIM + k0 + kk);
      lds_a[(kk + 0) * 68 + r] = v.x;
      lds_a[(kk + 1) * 68 + r] = v.y;
      lds_a[(kk + 2) * 68 + r] = v.z;
      lds_a[(kk + 3) * 68 + r] = v.w;
    }
    if (!BT) {
#pragma unroll
      for (int i = 0; i < 4; i++) {
        int idx = tid + i * 256;
        int kk  = idx >> 5;
        int j   = (idx & 31) << 2;
        int gj  = colBase + j;
        float4 v = make_float4(0.f, 0.f, 0.f, 0.f);
        if (gj < OUT) v = *(const float4*)(W + (size_t)(k0 + kk) * OUT + gj);
        *((float4*)&lds_b[kk * 132 + j]) = v;
      }
    } else {
#pragma unroll
      for (int i = 0; i < 4; i++) {
        int idx = tid + i * 256;
        int j   = idx >> 3;
        int k4  = (idx & 7) << 2;
        int gj  = colBase + j;
        float4 v = make_float4(0.f, 0.f, 0.f, 0.f);
        if (gj < OUT) v = *(const float4*)(W + (size_t)gj * HDIM + k0 + k4);
        lds_b[(k4 + 0) * 132 + j] = v.x;
        lds_b[(k4 + 1) * 132 + j] = v.y;
        lds_b[(k4 + 2) * 132 + j] = v.z;
        lds_b[(k4 + 3) * 132 + j] = v.w;
      }
    }
    __syncthreads();
#pragma unroll 8
    for (int kk = 0; kk < 32; kk++) {
      float4 a4 = *(const float4*)&lds_a[kk * 68 + ty * 4];
      float4 b0 = *(const float4*)&lds_b[kk * 132 + tx * 8];
      float4 b1 = *(const float4*)&lds_b[kk * 132 + tx * 8 + 4];
      float av[4] = {a4.x, a4.y, a4.z, a4.w};
      float bv[8] = {b0.x, b0.y, b0.z, b0.w, b1.x, b1.y, b1.z, b1.w};
#pragma unroll
      for (int r = 0; r < 4; r++)
#pragma unroll
        for (int c = 0; c < 8; c++)
          acc[r][c] = fmaf(av[r], bv[c], acc[r][c]);
    }
    __syncthreads();
  }

  int col = colBase + tx * 8;
  if (col >= OUT) return;
  float bv[8];
#pragma unroll
  for (int c = 0; c < 8; c++) bv[c] = bias ? bias[col + c] : 0.f;
#pragma unroll
  for (int r = 0; r < 4; r++) {
    int gr = rowBase + ty * 4 + r;
    if (gr >= M) continue;
    float* yp = Y + (size_t)gr * OUT + col;
    float4 o0 = make_float4(acc[r][0] + bv[0], acc[r][1] + bv[1],
                            acc[r][2] + bv[2], acc[r][3] + bv[3]);
    float4 o1 = make_float4(acc[r][4] + bv[4], acc[r][5] + bv[5],
                            acc[r][6] + bv[6], acc[r][7] + bv[7]);
    *(float4*)yp       = o0;
    *(float4*)(yp + 4) = o1;
    if (xpack) {                       // packed bf16 mirror (emb path)
      uint4 p;
      p.x = (unsigned)f2bf(o0.x) | ((unsigned)f2bf(o0.y) << 16);
      p.y = (unsigned)f2bf(o0.z) | ((unsigned)f2bf(o0.w) << 16);
      p.z = (unsigned)f2bf(o1.x) | ((unsigned)f2bf(o1.y) << 16);
      p.w = (unsigned)f2bf(o1.z) | ((unsigned)f2bf(o1.w) << 16);
      *(uint4*)&xpack[(size_t)gr * 64 + (col >> 1)] = p;
    }
  }
}

// ---------------------------------------------------------------------------
// CSR build, two-pass bucket sort (see round-2 notes: kills the random 8-B
// global scatter and csr_hist's 3.2M random atomics).
// Edge record in tmp: x = src | (local_dst << 17)  (17+9 = 26 bits), y = w.
// Final epak record: x = src << 8 (byte offset of the 256-B xbp row,
// pre-scaled so agg_pull's gather address is a single add), y = w.
// ---------------------------------------------------------------------------
__global__ __launch_bounds__(256) void csr_part1(
    const int* __restrict__ ei, const float* __restrict__ ew,
    int* __restrict__ bcnt,        // [NB*16] padded counters (one line each)
    int2* __restrict__ tmp)        // [NB*BSLOT]
{
  __shared__ int hist[NB];
  __shared__ int gbase[NB];
  const int tid = threadIdx.x;
  for (int i = tid; i < NB; i += 256) hist[i] = 0;
  __syncthreads();
  const int e0 = blockIdx.x * 2048 + tid * 8;   // 8 consecutive edges/thread
  const bool act = (e0 < N_EDGES);              // tail remainder is %8==0
  int4 s0, s1, d0, d1; float4 w0, w1;
  int rb[8];
  if (act) {
    s0 = *(const int4*)(ei + e0);
    s1 = *(const int4*)(ei + e0 + 4);
    d0 = *(const int4*)(ei + N_EDGES + e0);
    d1 = *(const int4*)(ei + N_EDGES + e0 + 4);
    w0 = *(const float4*)(ew + e0);
    w1 = *(const float4*)(ew + e0 + 4);
    int dv[8] = {d0.x, d0.y, d0.z, d0.w, d1.x, d1.y, d1.z, d1.w};
#pragma unroll
    for (int j = 0; j < 8; j++) {
      int b = dv[j] >> BSH;
      int r = atomicAdd(&hist[b], 1);
      rb[j] = (r << 8) | b;                     // rank<2048 (11b), b<196 (8b)
    }
  }
  __syncthreads();
  for (int i = tid; i < NB; i += 256) {
    int c = hist[i];
    gbase[i] = c ? atomicAdd(&bcnt[i * 16], c) : 0;  // one reserve per bucket
  }
  __syncthreads();
  if (act) {
    int sv[8] = {s0.x, s0.y, s0.z, s0.w, s1.x, s1.y, s1.z, s1.w};
    int dv[8] = {d0.x, d0.y, d0.z, d0.w, d1.x, d1.y, d1.z, d1.w};
    int wv[8] = {__float_as_int(w0.x), __float_as_int(w0.y),
                 __float_as_int(w0.z), __float_as_int(w0.w),
                 __float_as_int(w1.x), __float_as_int(w1.y),
                 __float_as_int(w1.z), __float_as_int(w1.w)};
#pragma unroll
    for (int j = 0; j < 8; j++) {
      int b  = rb[j] & 255;
      int of = gbase[b] + (rb[j] >> 8);
      if (of < BSLOT)                            // memory-safety guard only
        tmp[b * BSLOT + of] =
            make_int2(sv[j] | ((dv[j] & 511) << 17), wv[j]);
    }
  }
}

// exclusive scan of bucket counts -> bucket start offsets; rowptr[N] = E
__global__ void csr_scanb(const int* __restrict__ bcnt,
                          int* __restrict__ bstart, int* __restrict__ rowptr)
{
  __shared__ int l[256];
  int t = threadIdx.x;
  int v = (t < NB) ? min(bcnt[t * 16], BSLOT) : 0;
  l[t] = v;
  __syncthreads();
  for (int off = 1; off < 256; off <<= 1) {
    int u = (t >= off) ? l[t - off] : 0;
    __syncthreads();
    l[t] += u;
    __syncthreads();
  }
  if (t < NB) bstart[t] = l[t] - v;
  if (t == 255) rowptr[N_NODES] = l[255];
}

// per bucket: LDS node-hist -> LDS scan -> rowptr slice (coalesced) ->
// final in-bucket placement (reads+writes stay in ~130 KB, L2-resident).
__global__ __launch_bounds__(256) void csr_part2(
    const int2* __restrict__ tmp, const int* __restrict__ bcnt,
    const int* __restrict__ bstart, int* __restrict__ rowptr,
    int2* __restrict__ epak)
{
  __shared__ int cnt[512];
  __shared__ int lofs[512];
  __shared__ int s2[256];
  const int b      = blockIdx.x;
  const int tid    = threadIdx.x;
  const int nbase  = b << BSH;
  const int nn     = min(512, N_NODES - nbase);
  const int ecount = min(bcnt[b * 16], BSLOT);
  const long tbase = (long)b * BSLOT;
  const int obase  = bstart[b];
  for (int i = tid; i < 512; i += 256) cnt[i] = 0;
  __syncthreads();
  // pass A: per-node histogram of this bucket
  for (int e = tid; e < ecount; e += 256) {
    int2 rec = tmp[tbase + e];
    atomicAdd(&cnt[(rec.x >> 17) & 511], 1);
  }
  __syncthreads();
  // exclusive scan over 512 node counts (pairs + Hillis-Steele on 256)
  int c0 = cnt[2 * tid], c1 = cnt[2 * tid + 1];
  s2[tid] = c0 + c1;
  __syncthreads();
  int inc = s2[tid];
  for (int off = 1; off < 256; off <<= 1) {
    int u = (tid >= off) ? s2[tid - off] : 0;
    __syncthreads();
    s2[tid] += u;
    __syncthreads();
  }
  int ex = s2[tid] - inc;
  lofs[2 * tid]     = ex;
  lofs[2 * tid + 1] = ex + c0;
  __syncthreads();
  // rowptr slice, coalesced (replaces csr_hist + global scan entirely)
  for (int i = tid; i < nn; i += 256) rowptr[nbase + i] = obase + lofs[i];
  for (int i = tid; i < 512; i += 256) cnt[i] = 0;
  __syncthreads();
  // pass B: place edges at final CSR positions (within-row order arbitrary).
  // src is pre-scaled to its xbp byte offset (src*256) for agg_pull.
  for (int e = tid; e < ecount; e += 256) {
    int2 rec = tmp[tbase + e];
    int ldst = (rec.x >> 17) & 511;
    int r = atomicAdd(&cnt[ldst], 1);
    epak[obase + lofs[ldst] + r] = make_int2((rec.x & 0x1FFFF) << 8, rec.y);
  }
}

// ---------------------------------------------------------------------------
// Pull aggregation v4: COLUMN-SLICED for per-XCD L2 residency.
// r9 counters: FETCH_SIZE 370 MB/dispatch vs 52 MB compulsory -> ~45% of
// the 819 MB gather demand missed L2 (xbp = 25.6 MB vs 4 MB per-XCD L2,
// and every XCD gathered from ALL of xbp). Fix: grid (4, N/4); blockIdx.x
// picks a 64-B column slice (exactly one cache line, no overfetch).
// wgid = bx + 4*by -> slice s pinned to XCDs {s, s+4}: per-XCD xbp working
// set drops 25.6 -> 6.4 MB. Slices own disjoint output cols -> no cross-
// slice reduction. Wave = 4 edge-groups x 16 dwords; 2-step shfl_xor
// reduce over groups; zbp write = one full 64-B line per (node, slice).
// epak is streamed 4x but via nontemporal loads (don't evict hot xbp).
// fp32 reassociation only vs v3 (bf16-quantization-dominated absmax).
// ---------------------------------------------------------------------------
__global__ __launch_bounds__(256) void agg_pull(
    const unsigned* __restrict__ xbp, const int* __restrict__ rowptr,
    const int2* __restrict__ epak, unsigned* __restrict__ zbp)
{
  const int s    = blockIdx.x;                  // col slice 0..3 (64 B each)
  const int node = blockIdx.y * 4 + (threadIdx.x >> 6);
  const int lane = threadIdx.x & 63;
  const int g    = lane >> 4;                   // edge subgroup 0..3
  const unsigned coff = s * 64 + (lane & 15) * 4;
  const char* xbc = (const char*)xbp;
  const long long* epq = (const long long*)epak;
  int e = rowptr[node];
  const int s1 = rowptr[node + 1];
  float v0 = 0.f, v1 = 0.f;
  for (; e + 8 <= s1; e += 8) {
    long long qa = __builtin_nontemporal_load(epq + e + g);
    long long qb = __builtin_nontemporal_load(epq + e + g + 4);
    unsigned pa = *(const unsigned*)(xbc + (unsigned)(int)qa + coff);
    unsigned pb = *(const unsigned*)(xbc + (unsigned)(int)qb + coff);
    float wa = __int_as_float((int)(qa >> 32));
    float wb = __int_as_float((int)(qb >> 32));
    v0 = fmaf(wa, bflo(pa), v0); v1 = fmaf(wa, bfhi(pa), v1);
    v0 = fmaf(wb, bflo(pb), v0); v1 = fmaf(wb, bfhi(pb), v1);
  }
  for (; e < s1; e += 4) {
    if (e + g < s1) {
      long long qa = __builtin_nontemporal_load(epq + e + g);
      unsigned pa = *(const unsigned*)(xbc + (unsigned)(int)qa + coff);
      float wa = __int_as_float((int)(qa >> 32));
      v0 = fmaf(wa, bflo(pa), v0); v1 = fmaf(wa, bfhi(pa), v1);
    }
  }
  // reduce across the 4 edge-groups (lanes differing in bits 4..5)
  v0 += __shfl_xor(v0, 16, 64); v0 += __shfl_xor(v0, 32, 64);
  v1 += __shfl_xor(v1, 16, 64); v1 += __shfl_xor(v1, 32, 64);
  if (g == 0)
    zbp[(size_t)node * 64 + s * 16 + (lane & 15)] =
        (unsigned)f2bf(v0) | ((unsigned)f2bf(v1) << 16);
}

// ---------------------------------------------------------------------------
// Fused GRU layer (bf16 MFMA), v3 partition: block = 32 rows (2 row-tiles),
// 4 waves each own 2 t-column-tiles for all 32 rows. Accumulators:
// 2rt x 2ti x 4 sets = 64 VGPR. launch_bounds(256,4) caps at 128 VGPR.
// 32 | 100000 exactly -> no row guards. Fast sigmoid/tanh (see helpers).
// ---------------------------------------------------------------------------
__global__ __launch_bounds__(256, 4) void gru_fused(
    const short* __restrict__ zb, short* __restrict__ xb,
    float* __restrict__ x,
    const short* __restrict__ Fb, const short* __restrict__ Wb,
    const float* __restrict__ bih, const float* __restrict__ bhh)
{
  const int wave = threadIdx.x >> 6, lane = threadIdx.x & 63;
  const int m  = lane & 15;
  const int g4 = lane >> 4;
  const int rowBase = blockIdx.x * 32;
  const int t0 = wave * 2;                 // this wave's t-pair (cols t0*16..)

  f32x4 aR[2][2], aZ[2][2], aN[2][2], aH[2][2];
#pragma unroll
  for (int rt = 0; rt < 2; rt++)
#pragma unroll
    for (int ti = 0; ti < 2; ti++) {
      aR[rt][ti] = (f32x4){0.f, 0.f, 0.f, 0.f};
      aZ[rt][ti] = (f32x4){0.f, 0.f, 0.f, 0.f};
      aN[rt][ti] = (f32x4){0.f, 0.f, 0.f, 0.f};
      aH[rt][ti] = (f32x4){0.f, 0.f, 0.f, 0.f};
    }

  size_t arowc[2];
#pragma unroll
  for (int rt = 0; rt < 2; rt++)
    arowc[rt] = (size_t)(rowBase + rt * 16 + m) * 128 + g4 * 8;

  // ---- phase 0: z @ F -> r,z,i_n ----
#pragma unroll
  for (int ks = 0; ks < 4; ks++) {
    bf16x8 a[2];
#pragma unroll
    for (int rt = 0; rt < 2; rt++)
      a[rt] = *(const bf16x8*)(zb + arowc[rt] + ks * 32);
    const int bo = ks * 512 + lane * 8;
#pragma unroll
    for (int ti = 0; ti < 2; ti++) {
      const short* bp = Fb + (t0 + ti) * 2048 + bo;
      bf16x8 br = *(const bf16x8*)(bp);
      bf16x8 bz = *(const bf16x8*)(bp + 16384);
      bf16x8 bn = *(const bf16x8*)(bp + 32768);
#pragma unroll
      for (int rt = 0; rt < 2; rt++) {
        aR[rt][ti] = __builtin_amdgcn_mfma_f32_16x16x32_bf16(a[rt], br, aR[rt][ti], 0, 0, 0);
        aZ[rt][ti] = __builtin_amdgcn_mfma_f32_16x16x32_bf16(a[rt], bz, aZ[rt][ti], 0, 0, 0);
        aN[rt][ti] = __builtin_amdgcn_mfma_f32_16x16x32_bf16(a[rt], bn, aN[rt][ti], 0, 0, 0);
      }
    }
  }
  // ---- phase 1: x @ Whh^T -> r,z,h_n ----
#pragma unroll
  for (int ks = 0; ks < 4; ks++) {
    bf16x8 a[2];
#pragma unroll
    for (int rt = 0; rt < 2; rt++)
      a[rt] = *(const bf16x8*)(xb + arowc[rt] + ks * 32);
    const int bo = ks * 512 + lane * 8;
#pragma unroll
    for (int ti = 0; ti < 2; ti++) {
      const short* bp = Wb + (t0 + ti) * 2048 + bo;
      bf16x8 br = *(const bf16x8*)(bp);
      bf16x8 bz = *(const bf16x8*)(bp + 16384);
      bf16x8 bn = *(const bf16x8*)(bp + 32768);
#pragma unroll
      for (int rt = 0; rt < 2; rt++) {
        aR[rt][ti] = __builtin_amdgcn_mfma_f32_16x16x32_bf16(a[rt], br, aR[rt][ti], 0, 0, 0);
        aZ[rt][ti] = __builtin_amdgcn_mfma_f32_16x16x32_bf16(a[rt], bz, aZ[rt][ti], 0, 0, 0);
        aH[rt][ti] = __builtin_amdgcn_mfma_f32_16x16x32_bf16(a[rt], bn, aH[rt][ti], 0, 0, 0);
      }
    }
  }

  // ---- epilogue: gates + state update (C/D: col=lane&15, row=g4*4+reg) ----
  // prefetch all 16 x_old values first so VMEM latency overlaps gate VALU
  float xo[2][2][4];
  size_t xoff[2][2];
#pragma unroll
  for (int ti = 0; ti < 2; ti++)
#pragma unroll
    for (int rt = 0; rt < 2; rt++) {
      size_t o = (size_t)(rowBase + rt * 16 + g4 * 4) * 128 + (t0 + ti) * 16 + m;
      xoff[ti][rt] = o;
#pragma unroll
      for (int r = 0; r < 4; r++) xo[ti][rt][r] = x[o + (size_t)r * 128];
    }
#pragma unroll
  for (int ti = 0; ti < 2; ti++) {
    int col = (t0 + ti) * 16 + m;
    float b_r = bih[col] + bhh[col];
    float b_z = bih[128 + col] + bhh[128 + col];
    float b_i = bih[256 + col];
    float b_h = bhh[256 + col];
#pragma unroll
    for (int rt = 0; rt < 2; rt++) {
#pragma unroll
      for (int r = 0; r < 4; r++) {
        float rg = fsigmoid(aR[rt][ti][r] + b_r);
        float zg = fsigmoid(aZ[rt][ti][r] + b_z);
        float ng = ftanh(aN[rt][ti][r] + b_i + rg * (aH[rt][ti][r] + b_h));
        float xn = (1.f - zg) * ng + zg * xo[ti][rt][r];
        size_t o = xoff[ti][rt] + (size_t)r * 128;
        x[o] = xn;
        xb[o] = (short)f2bf(xn);
      }
    }
  }
}

// ---------------------------------------------------------------------------
// BatchNorm stats (fp32 master x)
// ---------------------------------------------------------------------------
__global__ __launch_bounds__(256) void bn_stats(
    const float* __restrict__ x, float* __restrict__ sums)
{
  __shared__ float ls[256], lq[256];
  int tid  = threadIdx.x;
  int col  = tid & 127, half = tid >> 7;
  int r0   = blockIdx.x * 128;
  int rend = min(N_NODES, r0 + 128);
  float s = 0.f, q = 0.f;
  for (int r = r0 + half; r < rend; r += 2) {
    float v = x[(size_t)r * HDIM + col];
    s += v; q += v * v;
  }
  ls[tid] = s; lq[tid] = q;
  __syncthreads();
  if (tid < 128) {
    atomicAdd(&sums[col],       ls[tid] + ls[tid + 128]);
    atomicAdd(&sums[128 + col], lq[tid] + lq[tid + 128]);
  }
}

__global__ void bn_finalize(float* __restrict__ sums,
                            const float* __restrict__ gamma,
                            const float* __restrict__ beta)
{
  int j = threadIdx.x;
  float mean = sums[j] / (float)N_NODES;
  float var  = sums[128 + j] / (float)N_NODES - mean * mean;
  float inv  = rsqrtf(var + 1e-5f);
  sums[256 + j] = gamma[j] * inv;
  sums[384 + j] = beta[j] - mean * gamma[j] * inv;
}

// ---------------------------------------------------------------------------
// Fused head v2: out = bn(x) @ mlpW + h @ e2 + c2. (r9: verified, left top-5;
// conflict-free LDS col layout, both weight mats LDS-resident once.)
// ---------------------------------------------------------------------------
__global__ __launch_bounds__(256) void head_fused(
    const float* __restrict__ x, const float* __restrict__ h,
    const float* __restrict__ sums,      // scale at [256..], shift at [384..]
    const float* __restrict__ mlpW,      // [128][40]
    const float* __restrict__ e2,        // [128][40]
    const float* __restrict__ c2,        // [40]
    float* __restrict__ out)             // [N][40]
{
  __shared__ alignas(16) float lds_b[2][128][44];   // 45056 B
  __shared__ alignas(16) float lds_a[32 * 260];     // 33280 B
  const int tid = threadIdx.x;
  const int tx = tid & 7;          // col group: cols {tx*4..+3, 32+tx}
  const int ty = tid >> 3;         // row group: rows {ty*8..+7}
  const int rowBase = blockIdx.x * 256;

  // load both B matrices once (coalesced; barrier below covers first use)
  for (int i = tid; i < 128 * 40; i += 256) {
    int kk = i / 40, j = i - kk * 40;
    lds_b[0][kk][j] = mlpW[i];
    lds_b[1][kk][j] = e2[i];
  }

  float acc[8][5];
#pragma unroll
  for (int r = 0; r < 8; r++)
#pragma unroll
    for (int c = 0; c < 5; c++) acc[r][c] = 0.f;

  for (int src = 0; src < 2; src++) {
    const float* A = src ? h : x;
    for (int k0 = 0; k0 < 128; k0 += 32) {
      __syncthreads();               // prev-iter readers done (+ B ready)
#pragma unroll
      for (int i = 0; i < 8; i++) {
        int idx = tid + i * 256;
        int r   = idx >> 3;          // 0..255
        int kk  = (idx & 7) << 2;
        int gr  = rowBase + r;
        float4 v = make_float4(0.f, 0.f, 0.f, 0.f);
        if (gr < N_NODES) v = *(const float4*)(A + (size_t)gr * HDIM + k0 + kk);
        if (src == 0) {              // fold BatchNorm apply into x tile load
          float4 sc = *(const float4*)(sums + 256 + k0 + kk);
          float4 sh = *(const float4*)(sums + 384 + k0 + kk);
          v.x = fmaf(v.x, sc.x, sh.x);
          v.y = fmaf(v.y, sc.y, sh.y);
          v.z = fmaf(v.z, sc.z, sh.z);
          v.w = fmaf(v.w, sc.w, sh.w);
        }
        lds_a[(kk + 0) * 260 + r] = v.x;
        lds_a[(kk + 1) * 260 + r] = v.y;
        lds_a[(kk + 2) * 260 + r] = v.z;
        lds_a[(kk + 3) * 260 + r] = v.w;
      }
      __syncthreads();
#pragma unroll 4
      for (int kk = 0; kk < 32; kk++) {
        float4 b4 = *(const float4*)&lds_b[src][k0 + kk][tx * 4];
        float  b1 = lds_b[src][k0 + kk][32 + tx];
        float4 a0 = *(const float4*)&lds_a[kk * 260 + ty * 8];
        float4 a1 = *(const float4*)&lds_a[kk * 260 + ty * 8 + 4];
        float av[8] = {a0.x, a0.y, a0.z, a0.w, a1.x, a1.y, a1.z, a1.w};
#pragma unroll
        for (int r = 0; r < 8; r++) {
          acc[r][0] = fmaf(av[r], b4.x, acc[r][0]);
          acc[r][1] = fmaf(av[r], b4.y, acc[r][1]);
          acc[r][2] = fmaf(av[r], b4.z, acc[r][2]);
          acc[r][3] = fmaf(av[r], b4.w, acc[r][3]);
          acc[r][4] = fmaf(av[r], b1,   acc[r][4]);
        }
      }
    }
  }

  const int c0 = tx * 4, c4 = 32 + tx;
  float bv0 = c2[c0], bv1 = c2[c0 + 1], bv2 = c2[c0 + 2], bv3 = c2[c0 + 3];
  float bv4 = c2[c4];
#pragma unroll
  for (int r = 0; r < 8; r++) {
    int gr = rowBase + ty * 8 + r;
    if (gr >= N_NODES) continue;
    float* yp = out + (size_t)gr * 40;
    float4 o = make_float4(acc[r][0] + bv0, acc[r][1] + bv1,
                           acc[r][2] + bv2, acc[r][3] + bv3);
    *(float4*)(yp + c0) = o;
    yp[c4] = acc[r][4] + bv4;
  }
}

// ---------------------------------------------------------------------------
// Residual fold constants: E2 = embW @ mlpW  [128][40], c2 = mlpB + embB@mlpW
// v2: one output per thread; data L2-hot; bit-identical fmaf chain.
// ---------------------------------------------------------------------------
__global__ __launch_bounds__(256) void prep_e2(
    const float* __restrict__ embW,
    const float* __restrict__ embB,
    const float* __restrict__ mlpW,
    const float* __restrict__ mlpB,
    float* __restrict__ e2, float* __restrict__ c2)
{
  int idx = blockIdx.x * 256 + threadIdx.x;
  if (idx < 5120) {
    int f = idx / 40, j = idx - f * 40;
    const float* er = embW + f * 128;
    float s = 0.f;
    for (int k = 0; k < 128; k++)
      s = fmaf(er[k], mlpW[k * 40 + j], s);
    e2[idx] = s;
  } else if (idx < 5160) {
    int j = idx - 5120;
    float s = mlpB[j];
    for (int k = 0; k < 128; k++)
      s = fmaf(embB[k], mlpW[k * 40 + j], s);
    c2[j] = s;
  }
}

// ---------------------------------------------------------------------------
extern "C" void kernel_launch(void* const* d_in, const int* in_sizes, int n_in,
                              void* d_out, int out_size, void* d_ws, size_t ws_size,
                              hipStream_t stream)
{
  const float* h     = (const float*)d_in[0];
  const int*   ei    = (const int*)d_in[1];
  const float* ew    = (const float*)d_in[2];
  const float* embW  = (const float*)d_in[3];
  const float* embB  = (const float*)d_in[4];
  const float* convW = (const float*)d_in[5];   // [3][128][128]
  const float* Wih   = (const float*)d_in[6];   // [384][128]
  const float* Whh   = (const float*)d_in[7];   // [384][128]
  const float* bih   = (const float*)d_in[8];
  const float* bhh   = (const float*)d_in[9];
  const float* gamma = (const float*)d_in[10];
  const float* beta  = (const float*)d_in[11];
  const float* mlpW  = (const float*)d_in[12];
  const float* mlpB  = (const float*)d_in[13];
  float* out = (float*)d_out;

  float* ws = (float*)d_ws;
  const size_t NH = (size_t)N_NODES * HDIM;      // 12.8M
  float*    x      = ws;                          // [N][128] fp32 master
  unsigned* xbp    = (unsigned*)(ws + NH);        // [N][64] packed bf16
  unsigned* zbp    = xbp + NH / 2;                // [N][64] packed bf16
  int2*     epak   = (int2*)(zbp + NH / 2);       // [E] {src_byteoff, w}
  int*      rowptr = (int*)(epak + N_EDGES);      // N+4
  int*      bcnt   = rowptr + N_NODES + 4;        // NB*16 padded counters
  int*      bstart = bcnt + NB * 16;              // NB (+pad)
  float*    Ffold  = (float*)(bstart + 256);      // [3][384][128] fp32
  short*    Fbp    = (short*)(Ffold + 3 * 384 * 128);  // frag-order bf16
  short*    Wbp    = Fbp + 3 * 384 * 128;         // frag-order bf16 of Whh
  float*    sums   = (float*)(Wbp + 384 * 128);
  float*    e2     = sums + 512;
  float*    c2     = e2 + 5120;
  // csr scratch: tmp [NB*BSLOT] int2 = 27.6 MB aliases xbp+zbp (both dead
  // until after the embedding GEMM / first agg_pull).
  int2*     tmp    = (int2*)xbp;

  dim3 blk(256);
  const int MB = (N_NODES + 63) / 64;
  const int GB = N_NODES / 32;                    // 3125, exact
  const int HB = (N_NODES + 255) / 256;           // 391
  const int RB = (384 * 128 + 255) / 256;
  const int P1B = (N_EDGES + 2047) / 2048;        // 1563 (tail %8 == 0)

  // ---- constants ----
  prep_e2<<<21, blk, 0, stream>>>(embW, embB, mlpW, mlpB, e2, c2);
  for (int l = 0; l < 3; l++)
    gemm_k128<true><<<dim3(6, 1), blk, 0, stream>>>(
        Wih, convW + (size_t)l * HDIM * HDIM, nullptr,
        Ffold + (size_t)l * 384 * HDIM, nullptr, 384, 128);
  for (int l = 0; l < 3; l++)
    repack_frag_b<<<RB, blk, 0, stream>>>(
        Ffold + (size_t)l * 384 * HDIM, Fbp + (size_t)l * 384 * HDIM);
  repack_frag_b<<<RB, blk, 0, stream>>>(Whh, Wbp);

  // ---- CSR build: bucket partition -> per-bucket place (no global scatter)
  zero_i32<<<(NB * 16 + 255) / 256, blk, 0, stream>>>(bcnt, NB * 16);
  csr_part1<<<P1B, blk, 0, stream>>>(ei, ew, bcnt, tmp);
  csr_scanb<<<1, 256, 0, stream>>>(bcnt, bstart, rowptr);
  csr_part2<<<NB, blk, 0, stream>>>(tmp, bcnt, bstart, rowptr, epak);

  // ---- embedding: x = h @ embW + embB ; bf16 mirror fused in epilogue ----
  gemm_k128<false><<<dim3(MB, 1), blk, 0, stream>>>(h, embW, embB, x, xbp,
                                                    N_NODES, 128);

  // ---- 3 GRU layers: col-sliced pull-agg (bf16) + fused MFMA GRU ----
  for (int l = 0; l < 3; l++) {
    agg_pull<<<dim3(4, N_NODES / 4), blk, 0, stream>>>(xbp, rowptr, epak, zbp);
    gru_fused<<<GB, blk, 0, stream>>>(
        (const short*)zbp, (short*)xbp, x,
        Fbp + (size_t)l * 384 * HDIM, Wbp, bih, bhh);
  }

  // ---- BatchNorm stats + fully fused head (BN apply + both GEMMs) ----
  zero_f32<<<2, blk, 0, stream>>>(sums, 512);
  bn_stats<<<(N_NODES + 127) / 128, blk, 0, stream>>>(x, sums);
  bn_finalize<<<1, 128, 0, stream>>>(sums, gamma, beta);
  head_fused<<<HB, blk, 0, stream>>>(x, h, sums, mlpW, e2, c2, out);
}

// Round 12
// 946.938 us; speedup vs baseline: 1.6602x; 1.6602x over previous
//
#include <hip/hip_runtime.h>
#include <math.h>

#define N_NODES 100000
#define N_EDGES 3200000
#define HDIM 128

// ---- bucket sort CSR build ----
#define NB 196        // buckets of 512 consecutive dst nodes (100000/512 -> 196)
#define BSH 9         // 512 nodes per bucket
#define BSLOT 18432   // tmp slots per bucket (avg fill 16327, +16 sigma headroom)

typedef __attribute__((ext_vector_type(8))) short bf16x8;
typedef __attribute__((ext_vector_type(4))) float f32x4;

__device__ __forceinline__ unsigned short f2bf(float f) {
  union { float f; unsigned u; } v; v.f = f;
  unsigned r = v.u + 0x7fffu + ((v.u >> 16) & 1u);
  return (unsigned short)(r >> 16);
}
__device__ __forceinline__ float bflo(unsigned p) {
  union { unsigned u; float f; } v; v.u = p << 16; return v.f;
}
__device__ __forceinline__ float bfhi(unsigned p) {
  union { unsigned u; float f; } v; v.u = p & 0xffff0000u; return v.f;
}
// fast sigmoid/tanh: v_exp + v_rcp (approx err ~1e-6 << bf16 quantum 4e-3
// already present in the data path).
__device__ __forceinline__ float fsigmoid(float v) {
  return __builtin_amdgcn_rcpf(1.f + __expf(-v));
}
__device__ __forceinline__ float ftanh(float v) {
  return 1.f - 2.f * __builtin_amdgcn_rcpf(1.f + __expf(2.f * v));
}

// ---------------------------------------------------------------------------
__global__ __launch_bounds__(256) void zero_i32(int* __restrict__ p, int n) {
  int i = blockIdx.x * 256 + threadIdx.x;
  if (i < n) p[i] = 0;
}
__global__ __launch_bounds__(256) void zero_f32(float* __restrict__ p, int n) {
  int i = blockIdx.x * 256 + threadIdx.x;
  if (i < n) p[i] = 0.f;
}

// ---------------------------------------------------------------------------
// Repack a [384][128] fp32 weight matrix (row-major [col][k]) into
// MFMA-B-fragment-ordered bf16 (lane*16B contiguous per fragment).
// ---------------------------------------------------------------------------
__global__ __launch_bounds__(256) void repack_frag_b(
    const float* __restrict__ src, short* __restrict__ dst)
{
  int o = blockIdx.x * 256 + threadIdx.x;      // 0 .. 384*128-1
  if (o >= 384 * 128) return;
  int j    = o & 7;
  int lane = (o >> 3) & 63;
  int ks   = (o >> 9) & 3;
  int t    = o >> 11;
  int m  = lane & 15;
  int g4 = lane >> 4;
  dst[o] = (short)f2bf(src[(t * 16 + m) * 128 + ks * 32 + g4 * 8 + j]);
}

// ---------------------------------------------------------------------------
// Tiled fp32 GEMM, K fixed at 128 (emb, weight folds). Optional bf16-pack
// epilogue mirror (xpack != nullptr -> also emit packed bf16 rows).
// v2: B-column remap. Old inner loop read lds_b at 32-B lane stride
// (tx*8 floats) -> 4-way bank conflict, the same signature measured at
// 1.52e7 in head_fused v1. Each thread now owns col groups {tx*4..+3} and
// {64+tx*4..+3}: read banks {0,4..28} twice = 2-way (free, m136). Same
// acc k-order, columns just remapped thread<->col -> numerically identical.
// ---------------------------------------------------------------------------
template<bool BT>
__global__ __launch_bounds__(256) void gemm_k128(
    const float* __restrict__ A, const float* __restrict__ W,
    const float* __restrict__ bias, float* __restrict__ Y,
    unsigned* __restrict__ xpack, int M, int OUT)
{
  __shared__ alignas(16) float lds_a[32 * 68];
  __shared__ alignas(16) float lds_b[32 * 132];
  const int tid = threadIdx.x;
  const int tx = tid & 15;
  const int ty = tid >> 4;
  const int rowBase = blockIdx.x * 64;
  const int colBase = blockIdx.y * 128;

  float acc[4][8];
#pragma unroll
  for (int r = 0; r < 4; r++)
#pragma unroll
    for (int c = 0; c < 8; c++) acc[r][c] = 0.f;

  for (int k0 = 0; k0 < 128; k0 += 32) {
#pragma unroll
    for (int i = 0; i < 2; i++) {
      int idx = tid + i * 256;
      int r   = idx >> 3;
      int kk  = (idx & 7) << 2;
      int gr  = rowBase + r;
      float4 v = make_float4(0.f, 0.f, 0.f, 0.f);
      if (gr < M) v = *(const float4*)(A + (size_t)gr * HDIM + k0 + kk);
      lds_a[(kk + 0) * 68 + r] = v.x;
      lds_a[(kk + 1) * 68 + r] = v.y;
      lds_a[(kk + 2) * 68 + r] = v.z;
      lds_a[(kk + 3) * 68 + r] = v.w;
    }
    if (!BT) {
#pragma unroll
      for (int i = 0; i < 4; i++) {
        int idx = tid + i * 256;
        int kk  = idx >> 5;
        int j   = (idx & 31) << 2;
        int gj  = colBase + j;
        float4 v = make_float4(0.f, 0.f, 0.f, 0.f);
        if (gj < OUT) v = *(const float4*)(W + (size_t)(k0 + kk) * OUT + gj);
        *((float4*)&lds_b[kk * 132 + j]) = v;
      }
    } else {
#pragma unroll
      for (int i = 0; i < 4; i++) {
        int idx = tid + i * 256;
        int j   = idx >> 3;
        int k4  = (idx & 7) << 2;
        int gj  = colBase + j;
        float4 v = make_float4(0.f, 0.f, 0.f, 0.f);
        if (gj < OUT) v = *(const float4*)(W + (size_t)gj * HDIM + k0 + k4);
        lds_b[(k4 + 0) * 132 + j] = v.x;
        lds_b[(k4 + 1) * 132 + j] = v.y;
        lds_b[(k4 + 2) * 132 + j] = v.z;
        lds_b[(k4 + 3) * 132 + j] = v.w;
      }
    }
    __syncthreads();
#pragma unroll 8
    for (int kk = 0; kk < 32; kk++) {
      float4 a4 = *(const float4*)&lds_a[kk * 68 + ty * 4];
      float4 b0 = *(const float4*)&lds_b[kk * 132 + tx * 4];        // 2-way
      float4 b1 = *(const float4*)&lds_b[kk * 132 + 64 + tx * 4];   // 2-way
      float av[4] = {a4.x, a4.y, a4.z, a4.w};
      float bv[8] = {b0.x, b0.y, b0.z, b0.w, b1.x, b1.y, b1.z, b1.w};
#pragma unroll
      for (int r = 0; r < 4; r++)
#pragma unroll
        for (int c = 0; c < 8; c++)
          acc[r][c] = fmaf(av[r], bv[c], acc[r][c]);
    }
    __syncthreads();
  }

  const int colA = colBase + tx * 4;
  const int colB = colBase + 64 + tx * 4;
  if (colA >= OUT) return;
  const bool hasB = (colB < OUT);
  float bv[8];
#pragma unroll
  for (int c = 0; c < 4; c++) bv[c] = bias ? bias[colA + c] : 0.f;
#pragma unroll
  for (int c = 0; c < 4; c++) bv[4 + c] = (bias && hasB) ? bias[colB + c] : 0.f;
#pragma unroll
  for (int r = 0; r < 4; r++) {
    int gr = rowBase + ty * 4 + r;
    if (gr >= M) continue;
    float* yp = Y + (size_t)gr * OUT;
    float4 o0 = make_float4(acc[r][0] + bv[0], acc[r][1] + bv[1],
                            acc[r][2] + bv[2], acc[r][3] + bv[3]);
    float4 o1 = make_float4(acc[r][4] + bv[4], acc[r][5] + bv[5],
                            acc[r][6] + bv[6], acc[r][7] + bv[7]);
    *(float4*)(yp + colA) = o0;
    if (hasB) *(float4*)(yp + colB) = o1;
    if (xpack) {                       // packed bf16 mirror (emb path)
      unsigned* xp = xpack + (size_t)gr * 64;
      uint2 pA, pB;
      pA.x = (unsigned)f2bf(o0.x) | ((unsigned)f2bf(o0.y) << 16);
      pA.y = (unsigned)f2bf(o0.z) | ((unsigned)f2bf(o0.w) << 16);
      pB.x = (unsigned)f2bf(o1.x) | ((unsigned)f2bf(o1.y) << 16);
      pB.y = (unsigned)f2bf(o1.z) | ((unsigned)f2bf(o1.w) << 16);
      *(uint2*)&xp[colA >> 1] = pA;
      if (hasB) *(uint2*)&xp[colB >> 1] = pB;
    }
  }
}

// ---------------------------------------------------------------------------
// CSR build, two-pass bucket sort (see round-2 notes: kills the random 8-B
// global scatter and csr_hist's 3.2M random atomics).
// Edge record in tmp: x = src | (local_dst << 17)  (17+9 = 26 bits), y = w.
// Final epak record: x = src << 8 (byte offset of the 256-B xbp row,
// pre-scaled so agg_pull's gather address is a single add), y = w.
// ---------------------------------------------------------------------------
__global__ __launch_bounds__(256) void csr_part1(
    const int* __restrict__ ei, const float* __restrict__ ew,
    int* __restrict__ bcnt,        // [NB*16] padded counters (one line each)
    int2* __restrict__ tmp)        // [NB*BSLOT]
{
  __shared__ int hist[NB];
  __shared__ int gbase[NB];
  const int tid = threadIdx.x;
  for (int i = tid; i < NB; i += 256) hist[i] = 0;
  __syncthreads();
  const int e0 = blockIdx.x * 2048 + tid * 8;   // 8 consecutive edges/thread
  const bool act = (e0 < N_EDGES);              // tail remainder is %8==0
  int4 s0, s1, d0, d1; float4 w0, w1;
  int rb[8];
  if (act) {
    s0 = *(const int4*)(ei + e0);
    s1 = *(const int4*)(ei + e0 + 4);
    d0 = *(const int4*)(ei + N_EDGES + e0);
    d1 = *(const int4*)(ei + N_EDGES + e0 + 4);
    w0 = *(const float4*)(ew + e0);
    w1 = *(const float4*)(ew + e0 + 4);
    int dv[8] = {d0.x, d0.y, d0.z, d0.w, d1.x, d1.y, d1.z, d1.w};
#pragma unroll
    for (int j = 0; j < 8; j++) {
      int b = dv[j] >> BSH;
      int r = atomicAdd(&hist[b], 1);
      rb[j] = (r << 8) | b;                     // rank<2048 (11b), b<196 (8b)
    }
  }
  __syncthreads();
  for (int i = tid; i < NB; i += 256) {
    int c = hist[i];
    gbase[i] = c ? atomicAdd(&bcnt[i * 16], c) : 0;  // one reserve per bucket
  }
  __syncthreads();
  if (act) {
    int sv[8] = {s0.x, s0.y, s0.z, s0.w, s1.x, s1.y, s1.z, s1.w};
    int dv[8] = {d0.x, d0.y, d0.z, d0.w, d1.x, d1.y, d1.z, d1.w};
    int wv[8] = {__float_as_int(w0.x), __float_as_int(w0.y),
                 __float_as_int(w0.z), __float_as_int(w0.w),
                 __float_as_int(w1.x), __float_as_int(w1.y),
                 __float_as_int(w1.z), __float_as_int(w1.w)};
#pragma unroll
    for (int j = 0; j < 8; j++) {
      int b  = rb[j] & 255;
      int of = gbase[b] + (rb[j] >> 8);
      if (of < BSLOT)                            // memory-safety guard only
        tmp[b * BSLOT + of] =
            make_int2(sv[j] | ((dv[j] & 511) << 17), wv[j]);
    }
  }
}

// exclusive scan of bucket counts -> bucket start offsets; rowptr[N] = E
__global__ void csr_scanb(const int* __restrict__ bcnt,
                          int* __restrict__ bstart, int* __restrict__ rowptr)
{
  __shared__ int l[256];
  int t = threadIdx.x;
  int v = (t < NB) ? min(bcnt[t * 16], BSLOT) : 0;
  l[t] = v;
  __syncthreads();
  for (int off = 1; off < 256; off <<= 1) {
    int u = (t >= off) ? l[t - off] : 0;
    __syncthreads();
    l[t] += u;
    __syncthreads();
  }
  if (t < NB) bstart[t] = l[t] - v;
  if (t == 255) rowptr[N_NODES] = l[255];
}

// per bucket: LDS node-hist -> LDS scan -> rowptr slice (coalesced) ->
// final in-bucket placement (reads+writes stay in ~130 KB, L2-resident).
__global__ __launch_bounds__(256) void csr_part2(
    const int2* __restrict__ tmp, const int* __restrict__ bcnt,
    const int* __restrict__ bstart, int* __restrict__ rowptr,
    int2* __restrict__ epak)
{
  __shared__ int cnt[512];
  __shared__ int lofs[512];
  __shared__ int s2[256];
  const int b      = blockIdx.x;
  const int tid    = threadIdx.x;
  const int nbase  = b << BSH;
  const int nn     = min(512, N_NODES - nbase);
  const int ecount = min(bcnt[b * 16], BSLOT);
  const long tbase = (long)b * BSLOT;
  const int obase  = bstart[b];
  for (int i = tid; i < 512; i += 256) cnt[i] = 0;
  __syncthreads();
  // pass A: per-node histogram of this bucket
  for (int e = tid; e < ecount; e += 256) {
    int2 rec = tmp[tbase + e];
    atomicAdd(&cnt[(rec.x >> 17) & 511], 1);
  }
  __syncthreads();
  // exclusive scan over 512 node counts (pairs + Hillis-Steele on 256)
  int c0 = cnt[2 * tid], c1 = cnt[2 * tid + 1];
  s2[tid] = c0 + c1;
  __syncthreads();
  int inc = s2[tid];
  for (int off = 1; off < 256; off <<= 1) {
    int u = (tid >= off) ? s2[tid - off] : 0;
    __syncthreads();
    s2[tid] += u;
    __syncthreads();
  }
  int ex = s2[tid] - inc;
  lofs[2 * tid]     = ex;
  lofs[2 * tid + 1] = ex + c0;
  __syncthreads();
  // rowptr slice, coalesced (replaces csr_hist + global scan entirely)
  for (int i = tid; i < nn; i += 256) rowptr[nbase + i] = obase + lofs[i];
  for (int i = tid; i < 512; i += 256) cnt[i] = 0;
  __syncthreads();
  // pass B: place edges at final CSR positions (within-row order arbitrary).
  // src is pre-scaled to its xbp byte offset (src*256) for agg_pull.
  for (int e = tid; e < ecount; e += 256) {
    int2 rec = tmp[tbase + e];
    int ldst = (rec.x >> 17) & 511;
    int r = atomicAdd(&cnt[ldst], 1);
    epak[obase + lofs[ldst] + r] = make_int2((rec.x & 0x1FFFF) << 8, rec.y);
  }
}

// ---------------------------------------------------------------------------
// Pull aggregation v3 (reverted from v4 col-slicing: r10 showed slicing
// doubles HBM fetch via 128-B L2-line granularity waste, and 6.4 MB/XCD
// still exceeds the 4-MB L2 -> no hit-rate gain. v3's 104 us is ~the
// L2-miss-path bandwidth limit for a 25.6-MB random gather set.)
// One wave/node; scalar path: node readfirstlane-anchored -> edge stream
// on s_load/SALU; gather addr = s[row] + lane*4 (loop-invariant).
// ---------------------------------------------------------------------------
__global__ __launch_bounds__(256) void agg_pull(
    const unsigned* __restrict__ xbp, const int* __restrict__ rowptr,
    const int2* __restrict__ epak, unsigned* __restrict__ zbp)
{
  const int node =
      __builtin_amdgcn_readfirstlane(blockIdx.x * 4 + (threadIdx.x >> 6));
  const int lane = threadIdx.x & 63;
  const unsigned lane4 = lane * 4;
  const char* xbc = (const char*)xbp;
  int e = rowptr[node];
  const int s1 = rowptr[node + 1];
  float v0 = 0.f, v1 = 0.f;
  // alignment pre-step: make e even so int4 loads on epak are 16-B aligned
  if ((e & 1) && e < s1) {
    int2 ep = epak[e++];
    unsigned p = *(const unsigned*)(xbc + (unsigned)ep.x + lane4);
    float w = __int_as_float(ep.y);
    v0 = fmaf(w, bflo(p), v0); v1 = fmaf(w, bfhi(p), v1);
  }
  const int n16 = e + ((s1 - e) & ~15);
  for (; e < n16; e += 16) {
    int4 q[8];
#pragma unroll
    for (int j = 0; j < 8; j++) q[j] = *(const int4*)(epak + e + 2 * j);
    unsigned p[16];
#pragma unroll
    for (int j = 0; j < 8; j++) {
      p[2 * j]     = *(const unsigned*)(xbc + (unsigned)q[j].x + lane4);
      p[2 * j + 1] = *(const unsigned*)(xbc + (unsigned)q[j].z + lane4);
    }
#pragma unroll
    for (int j = 0; j < 8; j++) {
      float wa = __int_as_float(q[j].y), wb = __int_as_float(q[j].w);
      v0 = fmaf(wa, bflo(p[2 * j]), v0);
      v1 = fmaf(wa, bfhi(p[2 * j]), v1);
      v0 = fmaf(wb, bflo(p[2 * j + 1]), v0);
      v1 = fmaf(wb, bfhi(p[2 * j + 1]), v1);
    }
  }
  const int n4 = e + ((s1 - e) & ~3);
  for (; e < n4; e += 4) {
    int4 qa = *(const int4*)(epak + e);
    int4 qb = *(const int4*)(epak + e + 2);
    unsigned p0 = *(const unsigned*)(xbc + (unsigned)qa.x + lane4);
    unsigned p1 = *(const unsigned*)(xbc + (unsigned)qa.z + lane4);
    unsigned p2 = *(const unsigned*)(xbc + (unsigned)qb.x + lane4);
    unsigned p3 = *(const unsigned*)(xbc + (unsigned)qb.z + lane4);
    float w0 = __int_as_float(qa.y), w1 = __int_as_float(qa.w);
    float w2 = __int_as_float(qb.y), w3 = __int_as_float(qb.w);
    v0 = fmaf(w0, bflo(p0), v0); v1 = fmaf(w0, bfhi(p0), v1);
    v0 = fmaf(w1, bflo(p1), v0); v1 = fmaf(w1, bfhi(p1), v1);
    v0 = fmaf(w2, bflo(p2), v0); v1 = fmaf(w2, bfhi(p2), v1);
    v0 = fmaf(w3, bflo(p3), v0); v1 = fmaf(w3, bfhi(p3), v1);
  }
  for (; e < s1; e++) {
    int2 ep = epak[e];
    unsigned p = *(const unsigned*)(xbc + (unsigned)ep.x + lane4);
    float w = __int_as_float(ep.y);
    v0 = fmaf(w, bflo(p), v0); v1 = fmaf(w, bfhi(p), v1);
  }
  zbp[(size_t)node * 64 + lane] =
      (unsigned)f2bf(v0) | ((unsigned)f2bf(v1) << 16);
}

// ---------------------------------------------------------------------------
// Fused GRU layer (bf16 MFMA), v3 partition: block = 32 rows (2 row-tiles),
// 4 waves each own 2 t-column-tiles for all 32 rows. Accumulators:
// 2rt x 2ti x 4 sets = 64 VGPR. launch_bounds(256,4) caps at 128 VGPR.
// 32 | 100000 exactly -> no row guards. Fast sigmoid/tanh (see helpers).
// ---------------------------------------------------------------------------
__global__ __launch_bounds__(256, 4) void gru_fused(
    const short* __restrict__ zb, short* __restrict__ xb,
    float* __restrict__ x,
    const short* __restrict__ Fb, const short* __restrict__ Wb,
    const float* __restrict__ bih, const float* __restrict__ bhh)
{
  const int wave = threadIdx.x >> 6, lane = threadIdx.x & 63;
  const int m  = lane & 15;
  const int g4 = lane >> 4;
  const int rowBase = blockIdx.x * 32;
  const int t0 = wave * 2;                 // this wave's t-pair (cols t0*16..)

  f32x4 aR[2][2], aZ[2][2], aN[2][2], aH[2][2];
#pragma unroll
  for (int rt = 0; rt < 2; rt++)
#pragma unroll
    for (int ti = 0; ti < 2; ti++) {
      aR[rt][ti] = (f32x4){0.f, 0.f, 0.f, 0.f};
      aZ[rt][ti] = (f32x4){0.f, 0.f, 0.f, 0.f};
      aN[rt][ti] = (f32x4){0.f, 0.f, 0.f, 0.f};
      aH[rt][ti] = (f32x4){0.f, 0.f, 0.f, 0.f};
    }

  size_t arowc[2];
#pragma unroll
  for (int rt = 0; rt < 2; rt++)
    arowc[rt] = (size_t)(rowBase + rt * 16 + m) * 128 + g4 * 8;

  // ---- phase 0: z @ F -> r,z,i_n ----
#pragma unroll
  for (int ks = 0; ks < 4; ks++) {
    bf16x8 a[2];
#pragma unroll
    for (int rt = 0; rt < 2; rt++)
      a[rt] = *(const bf16x8*)(zb + arowc[rt] + ks * 32);
    const int bo = ks * 512 + lane * 8;
#pragma unroll
    for (int ti = 0; ti < 2; ti++) {
      const short* bp = Fb + (t0 + ti) * 2048 + bo;
      bf16x8 br = *(const bf16x8*)(bp);
      bf16x8 bz = *(const bf16x8*)(bp + 16384);
      bf16x8 bn = *(const bf16x8*)(bp + 32768);
#pragma unroll
      for (int rt = 0; rt < 2; rt++) {
        aR[rt][ti] = __builtin_amdgcn_mfma_f32_16x16x32_bf16(a[rt], br, aR[rt][ti], 0, 0, 0);
        aZ[rt][ti] = __builtin_amdgcn_mfma_f32_16x16x32_bf16(a[rt], bz, aZ[rt][ti], 0, 0, 0);
        aN[rt][ti] = __builtin_amdgcn_mfma_f32_16x16x32_bf16(a[rt], bn, aN[rt][ti], 0, 0, 0);
      }
    }
  }
  // ---- phase 1: x @ Whh^T -> r,z,h_n ----
#pragma unroll
  for (int ks = 0; ks < 4; ks++) {
    bf16x8 a[2];
#pragma unroll
    for (int rt = 0; rt < 2; rt++)
      a[rt] = *(const bf16x8*)(xb + arowc[rt] + ks * 32);
    const int bo = ks * 512 + lane * 8;
#pragma unroll
    for (int ti = 0; ti < 2; ti++) {
      const short* bp = Wb + (t0 + ti) * 2048 + bo;
      bf16x8 br = *(const bf16x8*)(bp);
      bf16x8 bz = *(const bf16x8*)(bp + 16384);
      bf16x8 bn = *(const bf16x8*)(bp + 32768);
#pragma unroll
      for (int rt = 0; rt < 2; rt++) {
        aR[rt][ti] = __builtin_amdgcn_mfma_f32_16x16x32_bf16(a[rt], br, aR[rt][ti], 0, 0, 0);
        aZ[rt][ti] = __builtin_amdgcn_mfma_f32_16x16x32_bf16(a[rt], bz, aZ[rt][ti], 0, 0, 0);
        aH[rt][ti] = __builtin_amdgcn_mfma_f32_16x16x32_bf16(a[rt], bn, aH[rt][ti], 0, 0, 0);
      }
    }
  }

  // ---- epilogue: gates + state update (C/D: col=lane&15, row=g4*4+reg) ----
  // prefetch all 16 x_old values first so VMEM latency overlaps gate VALU
  float xo[2][2][4];
  size_t xoff[2][2];
#pragma unroll
  for (int ti = 0; ti < 2; ti++)
#pragma unroll
    for (int rt = 0; rt < 2; rt++) {
      size_t o = (size_t)(rowBase + rt * 16 + g4 * 4) * 128 + (t0 + ti) * 16 + m;
      xoff[ti][rt] = o;
#pragma unroll
      for (int r = 0; r < 4; r++) xo[ti][rt][r] = x[o + (size_t)r * 128];
    }
#pragma unroll
  for (int ti = 0; ti < 2; ti++) {
    int col = (t0 + ti) * 16 + m;
    float b_r = bih[col] + bhh[col];
    float b_z = bih[128 + col] + bhh[128 + col];
    float b_i = bih[256 + col];
    float b_h = bhh[256 + col];
#pragma unroll
    for (int rt = 0; rt < 2; rt++) {
#pragma unroll
      for (int r = 0; r < 4; r++) {
        float rg = fsigmoid(aR[rt][ti][r] + b_r);
        float zg = fsigmoid(aZ[rt][ti][r] + b_z);
        float ng = ftanh(aN[rt][ti][r] + b_i + rg * (aH[rt][ti][r] + b_h));
        float xn = (1.f - zg) * ng + zg * xo[ti][rt][r];
        size_t o = xoff[ti][rt] + (size_t)r * 128;
        x[o] = xn;
        xb[o] = (short)f2bf(xn);
      }
    }
  }
}

// ---------------------------------------------------------------------------
// BatchNorm stats (fp32 master x)
// ---------------------------------------------------------------------------
__global__ __launch_bounds__(256) void bn_stats(
    const float* __restrict__ x, float* __restrict__ sums)
{
  __shared__ float ls[256], lq[256];
  int tid  = threadIdx.x;
  int col  = tid & 127, half = tid >> 7;
  int r0   = blockIdx.x * 128;
  int rend = min(N_NODES, r0 + 128);
  float s = 0.f, q = 0.f;
  for (int r = r0 + half; r < rend; r += 2) {
    float v = x[(size_t)r * HDIM + col];
    s += v; q += v * v;
  }
  ls[tid] = s; lq[tid] = q;
  __syncthreads();
  if (tid < 128) {
    atomicAdd(&sums[col],       ls[tid] + ls[tid + 128]);
    atomicAdd(&sums[128 + col], lq[tid] + lq[tid + 128]);
  }
}

__global__ void bn_finalize(float* __restrict__ sums,
                            const float* __restrict__ gamma,
                            const float* __restrict__ beta)
{
  int j = threadIdx.x;
  float mean = sums[j] / (float)N_NODES;
  float var  = sums[128 + j] / (float)N_NODES - mean * mean;
  float inv  = rsqrtf(var + 1e-5f);
  sums[256 + j] = gamma[j] * inv;
  sums[384 + j] = beta[j] - mean * gamma[j] * inv;
}

// ---------------------------------------------------------------------------
// Fused head v2: out = bn(x) @ mlpW + h @ e2 + c2. (r9: verified;
// conflict-free LDS col layout, both weight mats LDS-resident once.)
// ---------------------------------------------------------------------------
__global__ __launch_bounds__(256) void head_fused(
    const float* __restrict__ x, const float* __restrict__ h,
    const float* __restrict__ sums,      // scale at [256..], shift at [384..]
    const float* __restrict__ mlpW,      // [128][40]
    const float* __restrict__ e2,        // [128][40]
    const float* __restrict__ c2,        // [40]
    float* __restrict__ out)             // [N][40]
{
  __shared__ alignas(16) float lds_b[2][128][44];   // 45056 B
  __shared__ alignas(16) float lds_a[32 * 260];     // 33280 B
  const int tid = threadIdx.x;
  const int tx = tid & 7;          // col group: cols {tx*4..+3, 32+tx}
  const int ty = tid >> 3;         // row group: rows {ty*8..+7}
  const int rowBase = blockIdx.x * 256;

  // load both B matrices once (coalesced; barrier below covers first use)
  for (int i = tid; i < 128 * 40; i += 256) {
    int kk = i / 40, j = i - kk * 40;
    lds_b[0][kk][j] = mlpW[i];
    lds_b[1][kk][j] = e2[i];
  }

  float acc[8][5];
#pragma unroll
  for (int r = 0; r < 8; r++)
#pragma unroll
    for (int c = 0; c < 5; c++) acc[r][c] = 0.f;

  for (int src = 0; src < 2; src++) {
    const float* A = src ? h : x;
    for (int k0 = 0; k0 < 128; k0 += 32) {
      __syncthreads();               // prev-iter readers done (+ B ready)
#pragma unroll
      for (int i = 0; i < 8; i++) {
        int idx = tid + i * 256;
        int r   = idx >> 3;          // 0..255
        int kk  = (idx & 7) << 2;
        int gr  = rowBase + r;
        float4 v = make_float4(0.f, 0.f, 0.f, 0.f);
        if (gr < N_NODES) v = *(const float4*)(A + (size_t)gr * HDIM + k0 + kk);
        if (src == 0) {              // fold BatchNorm apply into x tile load
          float4 sc = *(const float4*)(sums + 256 + k0 + kk);
          float4 sh = *(const float4*)(sums + 384 + k0 + kk);
          v.x = fmaf(v.x, sc.x, sh.x);
          v.y = fmaf(v.y, sc.y, sh.y);
          v.z = fmaf(v.z, sc.z, sh.z);
          v.w = fmaf(v.w, sc.w, sh.w);
        }
        lds_a[(kk + 0) * 260 + r] = v.x;
        lds_a[(kk + 1) * 260 + r] = v.y;
        lds_a[(kk + 2) * 260 + r] = v.z;
        lds_a[(kk + 3) * 260 + r] = v.w;
      }
      __syncthreads();
#pragma unroll 4
      for (int kk = 0; kk < 32; kk++) {
        float4 b4 = *(const float4*)&lds_b[src][k0 + kk][tx * 4];
        float  b1 = lds_b[src][k0 + kk][32 + tx];
        float4 a0 = *(const float4*)&lds_a[kk * 260 + ty * 8];
        float4 a1 = *(const float4*)&lds_a[kk * 260 + ty * 8 + 4];
        float av[8] = {a0.x, a0.y, a0.z, a0.w, a1.x, a1.y, a1.z, a1.w};
#pragma unroll
        for (int r = 0; r < 8; r++) {
          acc[r][0] = fmaf(av[r], b4.x, acc[r][0]);
          acc[r][1] = fmaf(av[r], b4.y, acc[r][1]);
          acc[r][2] = fmaf(av[r], b4.z, acc[r][2]);
          acc[r][3] = fmaf(av[r], b4.w, acc[r][3]);
          acc[r][4] = fmaf(av[r], b1,   acc[r][4]);
        }
      }
    }
  }

  const int c0 = tx * 4, c4 = 32 + tx;
  float bv0 = c2[c0], bv1 = c2[c0 + 1], bv2 = c2[c0 + 2], bv3 = c2[c0 + 3];
  float bv4 = c2[c4];
#pragma unroll
  for (int r = 0; r < 8; r++) {
    int gr = rowBase + ty * 8 + r;
    if (gr >= N_NODES) continue;
    float* yp = out + (size_t)gr * 40;
    float4 o = make_float4(acc[r][0] + bv0, acc[r][1] + bv1,
                           acc[r][2] + bv2, acc[r][3] + bv3);
    *(float4*)(yp + c0) = o;
    yp[c4] = acc[r][4] + bv4;
  }
}

// ---------------------------------------------------------------------------
// Residual fold constants: E2 = embW @ mlpW  [128][40], c2 = mlpB + embB@mlpW
// v2: one output per thread; data L2-hot; bit-identical fmaf chain.
// ---------------------------------------------------------------------------
__global__ __launch_bounds__(256) void prep_e2(
    const float* __restrict__ embW,
    const float* __restrict__ embB,
    const float* __restrict__ mlpW,
    const float* __restrict__ mlpB,
    float* __restrict__ e2, float* __restrict__ c2)
{
  int idx = blockIdx.x * 256 + threadIdx.x;
  if (idx < 5120) {
    int f = idx / 40, j = idx - f * 40;
    const float* er = embW + f * 128;
    float s = 0.f;
    for (int k = 0; k < 128; k++)
      s = fmaf(er[k], mlpW[k * 40 + j], s);
    e2[idx] = s;
  } else if (idx < 5160) {
    int j = idx - 5120;
    float s = mlpB[j];
    for (int k = 0; k < 128; k++)
      s = fmaf(embB[k], mlpW[k * 40 + j], s);
    c2[j] = s;
  }
}

// ---------------------------------------------------------------------------
extern "C" void kernel_launch(void* const* d_in, const int* in_sizes, int n_in,
                              void* d_out, int out_size, void* d_ws, size_t ws_size,
                              hipStream_t stream)
{
  const float* h     = (const float*)d_in[0];
  const int*   ei    = (const int*)d_in[1];
  const float* ew    = (const float*)d_in[2];
  const float* embW  = (const float*)d_in[3];
  const float* embB  = (const float*)d_in[4];
  const float* convW = (const float*)d_in[5];   // [3][128][128]
  const float* Wih   = (const float*)d_in[6];   // [384][128]
  const float* Whh   = (const float*)d_in[7];   // [384][128]
  const float* bih   = (const float*)d_in[8];
  const float* bhh   = (const float*)d_in[9];
  const float* gamma = (const float*)d_in[10];
  const float* beta  = (const float*)d_in[11];
  const float* mlpW  = (const float*)d_in[12];
  const float* mlpB  = (const float*)d_in[13];
  float* out = (float*)d_out;

  float* ws = (float*)d_ws;
  const size_t NH = (size_t)N_NODES * HDIM;      // 12.8M
  float*    x      = ws;                          // [N][128] fp32 master
  unsigned* xbp    = (unsigned*)(ws + NH);        // [N][64] packed bf16
  unsigned* zbp    = xbp + NH / 2;                // [N][64] packed bf16
  int2*     epak   = (int2*)(zbp + NH / 2);       // [E] {src_byteoff, w}
  int*      rowptr = (int*)(epak + N_EDGES);      // N+4
  int*      bcnt   = rowptr + N_NODES + 4;        // NB*16 padded counters
  int*      bstart = bcnt + NB * 16;              // NB (+pad)
  float*    Ffold  = (float*)(bstart + 256);      // [3][384][128] fp32
  short*    Fbp    = (short*)(Ffold + 3 * 384 * 128);  // frag-order bf16
  short*    Wbp    = Fbp + 3 * 384 * 128;         // frag-order bf16 of Whh
  float*    sums   = (float*)(Wbp + 384 * 128);
  float*    e2     = sums + 512;
  float*    c2     = e2 + 5120;
  // csr scratch: tmp [NB*BSLOT] int2 = 27.6 MB aliases xbp+zbp (both dead
  // until after the embedding GEMM / first agg_pull).
  int2*     tmp    = (int2*)xbp;

  dim3 blk(256);
  const int MB = (N_NODES + 63) / 64;
  const int GB = N_NODES / 32;                    // 3125, exact
  const int HB = (N_NODES + 255) / 256;           // 391
  const int RB = (384 * 128 + 255) / 256;
  const int P1B = (N_EDGES + 2047) / 2048;        // 1563 (tail %8 == 0)

  // ---- constants ----
  prep_e2<<<21, blk, 0, stream>>>(embW, embB, mlpW, mlpB, e2, c2);
  for (int l = 0; l < 3; l++)
    gemm_k128<true><<<dim3(6, 1), blk, 0, stream>>>(
        Wih, convW + (size_t)l * HDIM * HDIM, nullptr,
        Ffold + (size_t)l * 384 * HDIM, nullptr, 384, 128);
  for (int l = 0; l < 3; l++)
    repack_frag_b<<<RB, blk, 0, stream>>>(
        Ffold + (size_t)l * 384 * HDIM, Fbp + (size_t)l * 384 * HDIM);
  repack_frag_b<<<RB, blk, 0, stream>>>(Whh, Wbp);

  // ---- CSR build: bucket partition -> per-bucket place (no global scatter)
  zero_i32<<<(NB * 16 + 255) / 256, blk, 0, stream>>>(bcnt, NB * 16);
  csr_part1<<<P1B, blk, 0, stream>>>(ei, ew, bcnt, tmp);
  csr_scanb<<<1, 256, 0, stream>>>(bcnt, bstart, rowptr);
  csr_part2<<<NB, blk, 0, stream>>>(tmp, bcnt, bstart, rowptr, epak);

  // ---- embedding: x = h @ embW + embB ; bf16 mirror fused in epilogue ----
  gemm_k128<false><<<dim3(MB, 1), blk, 0, stream>>>(h, embW, embB, x, xbp,
                                                    N_NODES, 128);

  // ---- 3 GRU layers: pull-agg (bf16) + fused MFMA GRU ----
  for (int l = 0; l < 3; l++) {
    agg_pull<<<N_NODES / 4, blk, 0, stream>>>(xbp, rowptr, epak, zbp);
    gru_fused<<<GB, blk, 0, stream>>>(
        (const short*)zbp, (short*)xbp, x,
        Fbp + (size_t)l * 384 * HDIM, Wbp, bih, bhh);
  }

  // ---- BatchNorm stats + fully fused head (BN apply + both GEMMs) ----
  zero_f32<<<2, blk, 0, stream>>>(sums, 512);
  bn_stats<<<(N_NODES + 127) / 128, blk, 0, stream>>>(x, sums);
  bn_finalize<<<1, 128, 0, stream>>>(sums, gamma, beta);
  head_fused<<<HB, blk, 0, stream>>>(x, h, sums, mlpW, e2, c2, out);
}